// Round 12
// baseline (318.402 us; speedup 1.0000x reference)
//
#include <hip/hip_runtime.h>
#include <hip/hip_bf16.h>

// Problem constants: x (B,N,D) fp32; per-head SwiGLU FFN H=512.
#define B_ 8192
#define N_ 16
#define D_ 256
#define H_ 512

using bf16x8 = __attribute__((ext_vector_type(8))) short;
using f32x4  = __attribute__((ext_vector_type(4))) float;

__device__ __forceinline__ void gload_lds16(const void* g, void* l) {
    __builtin_amdgcn_global_load_lds(
        (const __attribute__((address_space(1))) void*)g,
        (__attribute__((address_space(3))) void*)l, 16, 0, 0);
}

__device__ __forceinline__ short f2bf(float f) {
    unsigned int u = __float_as_uint(f);
    u += 0x7fffu + ((u >> 16) & 1u);   // round-to-nearest-even
    return (short)(u >> 16);
}

__device__ __forceinline__ float bf2f(short s) {
    return __uint_as_float(((unsigned int)(unsigned short)s) << 16);
}

__device__ __forceinline__ unsigned int pack2(float lo, float hi) {
    return (unsigned int)(unsigned short)f2bf(lo)
         | ((unsigned int)(unsigned short)f2bf(hi) << 16);
}

__device__ __forceinline__ f32x4 mfma(bf16x8 a, bf16x8 b, f32x4 c) {
    return __builtin_amdgcn_mfma_f32_16x16x32_bf16(a, b, c, 0, 0, 0);
}

// Swizzled fragment read from a [rows][GR granules] LDS panel: global granule
// g of row r lives in slot (g&~7)|((g^r)&7) (XOR within 8-granule groups).
// R10/R11-verified conflict-free (SQ_LDS_BANK_CONFLICT = 0).
template<int GR>
__device__ __forceinline__ bf16x8 rdg(const short* base, int row, int g) {
    int gp = (g & ~7) | ((g ^ row) & 7);
    return *(const bf16x8*)&base[row * GR * 8 + gp * 8];
}

// Stage a [128 rows][64 cols] panel (one BK=64 K-tile), global stride S,
// k-offset k0: linear LDS dest + inverse-XOR global source. 256 threads.
template<int S>
__device__ __forceinline__ void stage64(const short* __restrict__ gsrc, int k0,
                                        short* lds, int t) {
#pragma unroll
    for (int rnd = 0; rnd < 4; ++rnd) {
        int flat = rnd * 256 + t;
        int row = flat >> 3, g = flat & 7;
        int sg = (g ^ row) & 7;
        gload_lds16(gsrc + (size_t)row * S + k0 + sg * 8, lds + flat * 8);
    }
}

// ---------------------------------------------------------------------------
// k_prep: fp32 weights -> bf16.
//   wgu: [n][1024 rows][256] where row ri = (h>>4)*32 + which*16 + (h&15),
//        which 0=W1(gate), 1=W3(up)  -> G/U rows adjacent at 16-granularity.
//   w2t: [n][d][h]  (B^T of (H,D))
// ---------------------------------------------------------------------------
__global__ __launch_bounds__(256) void k_prep(const float* __restrict__ w1,
                                              const float* __restrict__ w3,
                                              const float* __restrict__ w2,
                                              short* __restrict__ wgu,
                                              short* __restrict__ w2t) {
    int o = blockIdx.x * 256 + threadIdx.x;      // 0 .. N*D*H-1 (2M)
    int n = o >> 17;                              // / (D*H = 131072)
    int r = o & 131071;
    int h = r >> 8, d = r & 255;
    size_t base = ((size_t)n * 1024 + (h >> 4) * 32 + (h & 15)) * 256 + d;
    wgu[base]            = f2bf(w1[(size_t)n * 131072 + (size_t)d * 512 + h]);
    wgu[base + 16 * 256] = f2bf(w3[(size_t)n * 131072 + (size_t)d * 512 + h]);
    int d2 = r >> 9, h2 = r & 511;                // [n][d][h] out layout
    w2t[o] = f2bf(w2[(size_t)n * 131072 + (size_t)h2 * 256 + d2]);
}

// ---------------------------------------------------------------------------
// k_mix: per-b block. rmsnorm1 -> head_mixing -> +x -> rmsnorm2.
// Wave-parallel float4 row sums + bank-staggered mix loop + packed bf16x2
// stores. Head-major outputs pb/pn [head][b][d].
// ---------------------------------------------------------------------------
__global__ __launch_bounds__(256) void k_mix(const float* __restrict__ x,
                                             const float* __restrict__ n1w,
                                             const float* __restrict__ n2w,
                                             unsigned int* __restrict__ pb_u,
                                             unsigned int* __restrict__ pn_u) {
    __shared__ __align__(16) float xs[N_ * D_];
    __shared__ __align__(16) float ps[N_ * D_];
    __shared__ float inv1[N_];
    __shared__ float inv2[N_];
    int b = blockIdx.x;
    int t = threadIdx.x;
    int w = t >> 6, lane = t & 63;

    const float4* xb4 = (const float4*)(x + (size_t)b * (N_ * D_));
    float4* xs4 = (float4*)xs;
    float4* ps4 = (float4*)ps;
#pragma unroll
    for (int i = 0; i < 4; ++i) xs4[t + i * 256] = xb4[t + i * 256];
    __syncthreads();

#pragma unroll
    for (int q = 0; q < 4; ++q) {
        int row = w * 4 + q;
        float4 v = xs4[row * 64 + lane];
        float s = v.x * v.x + v.y * v.y + v.z * v.z + v.w * v.w;
        s += __shfl_xor(s, 1);  s += __shfl_xor(s, 2);
        s += __shfl_xor(s, 4);  s += __shfl_xor(s, 8);
        s += __shfl_xor(s, 16); s += __shfl_xor(s, 32);
        if (lane == 0) inv1[row] = rsqrtf(s * (1.0f / 256.0f) + 1e-6f);
    }
    __syncthreads();

    {
        int n = t >> 4, j = t & 15;
        float i1 = inv1[n];
#pragma unroll 1
        for (int m = 0; m < 16; ++m) {
            int mm = (m + n) & 15;
            float v = xs[n * 256 + mm * 16 + j] * i1 * n1w[mm * 16 + j]
                    + xs[mm * 256 + t];
            ps[mm * 256 + t] = v;
        }
    }
    __syncthreads();

#pragma unroll
    for (int q = 0; q < 4; ++q) {
        int row = w * 4 + q;
        float4 v = ps4[row * 64 + lane];
        float s = v.x * v.x + v.y * v.y + v.z * v.z + v.w * v.w;
        s += __shfl_xor(s, 1);  s += __shfl_xor(s, 2);
        s += __shfl_xor(s, 4);  s += __shfl_xor(s, 8);
        s += __shfl_xor(s, 16); s += __shfl_xor(s, 32);
        if (lane == 0) inv2[row] = rsqrtf(s * (1.0f / 256.0f) + 1e-6f);
    }
    __syncthreads();

    int dh = t & 127, mh = t >> 7;
    float wA = n2w[2 * dh], wB = n2w[2 * dh + 1];
#pragma unroll
    for (int i = 0; i < 8; ++i) {
        int m = mh * 8 + i;
        float2 f = *(const float2*)&ps[m * 256 + 2 * dh];
        float iv = inv2[m];
        size_t off = ((size_t)m * B_ + b) * (D_ / 2) + dh;
        pb_u[off] = pack2(f.x, f.y);
        pn_u[off] = pack2(f.x * iv * wA, f.y * iv * wB);
    }
}

// ---------------------------------------------------------------------------
// k_gu (A-resident): block = (head, 128 b-rows). A tile 128x256 (64 KiB)
// staged ONCE and kept in LDS; B streamed in 16 KiB chunks (8 nt x 4 kt).
// Per barrier-pair: 4 gloads/thread (vs 8 before), A-reads never wait.
// acc per nt chunk; silu(G)*U epilogue per nt -> hact [head][m][h] bf16.
// LDS 80 KiB dynamic -> 2 blocks/CU.
// ---------------------------------------------------------------------------
__global__ __launch_bounds__(256, 2) void k_gu(const short* __restrict__ pn,
                                               const short* __restrict__ wgu,
                                               short* __restrict__ hact) {
    extern __shared__ short sm[];
    short* As = sm;            // [128][32 granules] = 32768 shorts (64 KiB)
    short* Bs = sm + 32768;    // [128][8 granules]  =  8192 shorts (16 KiB)

    // XCD-aware bijective swizzle: 1024 blocks, 128 per XCD chunk.
    int bid = blockIdx.x;
    int bx = (bid & 7) * 128 + (bid >> 3);
    int head = bx >> 6;
    int mt = bx & 63;

    int t = threadIdx.x;
    int w = t >> 6, lane = t & 63;
    int l16 = lane & 15, kq = lane >> 4;
    int wm = w >> 1, wn = w & 1;
    int rowA0 = wm * 64, rowB0 = wn * 64;

    const short* Ag = pn + ((size_t)head * B_ + (size_t)mt * 128) * D_;

    // stage the full A tile (128 rows x 256 k), inverse-XOR source
#pragma unroll
    for (int rnd = 0; rnd < 16; ++rnd) {
        int flat = rnd * 256 + t;
        int row = flat >> 5, g = flat & 31;
        int sg = (g & ~7) | ((g ^ row) & 7);
        gload_lds16(Ag + (size_t)row * D_ + sg * 8, As + flat * 8);
    }

    size_t hb = (size_t)head * B_ * H_;

#pragma unroll 1
    for (int nt = 0; nt < 8; ++nt) {
        const short* Bg = wgu + ((size_t)head * 1024 + (size_t)nt * 128) * D_;

        f32x4 acc[4][4];
#pragma unroll
        for (int i = 0; i < 4; ++i)
#pragma unroll
            for (int j = 0; j < 4; ++j) acc[i][j] = (f32x4){0.f, 0.f, 0.f, 0.f};

#pragma unroll
        for (int kt = 0; kt < 4; ++kt) {
            stage64<256>(Bg, kt * 64, Bs, t);
            __syncthreads();   // drains B loads (and A on first pass)
#pragma unroll
            for (int kh = 0; kh < 2; ++kh) {
                int gB = kh * 4 + kq;
                int gA = kt * 8 + kh * 4 + kq;
                bf16x8 aF[4], bF[4];
#pragma unroll
                for (int j = 0; j < 4; ++j)
                    bF[j] = rdg<8>(Bs, rowB0 + j * 16 + l16, gB);
#pragma unroll
                for (int i = 0; i < 4; ++i)
                    aF[i] = rdg<32>(As, rowA0 + i * 16 + l16, gA);
#pragma unroll
                for (int i = 0; i < 4; ++i)
#pragma unroll
                    for (int j = 0; j < 4; ++j)
                        acc[i][j] = mfma(aF[i], bF[j], acc[i][j]);
            }
            __syncthreads();   // protect Bs WAR before next stage
        }

        // epilogue for this nt: B-row pairs (0,1),(2,3) = (G,U) of 16 h's
#pragma unroll
        for (int mf = 0; mf < 4; ++mf) {
            int m = mt * 128 + wm * 64 + mf * 16 + kq * 4;
#pragma unroll
            for (int p = 0; p < 2; ++p) {
                int h = nt * 64 + (wn * 2 + p) * 16 + l16;
#pragma unroll
                for (int r = 0; r < 4; ++r) {
                    float g = acc[mf][2 * p][r];
                    float u = acc[mf][2 * p + 1][r];
                    float hv = g * (1.0f / (1.0f + __expf(-g))) * u;
                    hact[hb + (size_t)(m + r) * H_ + h] = f2bf(hv);
                }
            }
        }
    }
}

// ---------------------------------------------------------------------------
// k_dn (prefetch double-buffer, R4-proven structure): Q = Hact @ W2 per head
// (M=8192/head, N=256, K=512) + pb -> out (B,N,D). 128x128 tile, BK=64.
// Issue next K-tile loads BEFORE computing current tile; one __syncthreads
// per tile (drains both). Overlaps the HBM hact stream with MFMA.
// LDS 64 KiB dynamic -> 2 blocks/CU.
// ---------------------------------------------------------------------------
__global__ __launch_bounds__(256, 2) void k_dn(const short* __restrict__ hact,
                                               const short* __restrict__ w2t,
                                               const short* __restrict__ pb,
                                               float* __restrict__ out) {
    extern __shared__ short sm[];
    // A slots: [0,8192),[8192,16384); B slots: [16384,24576),[24576,32768)

    // XCD-aware bijective swizzle: 2048 blocks, 256 per XCD chunk.
    int bid = blockIdx.x;
    int bx = (bid & 7) * 256 + (bid >> 3);
    int head = bx >> 7;
    int mt = (bx >> 1) & 63;      // nt fastest -> A-tile L2 reuse
    int nt = bx & 1;

    int t = threadIdx.x;
    int w = t >> 6, lane = t & 63;
    int l16 = lane & 15, kq = lane >> 4;
    int wm = w >> 1, wn = w & 1;
    int rowA0 = wm * 64, rowB0 = wn * 64;

    f32x4 acc[4][4];
#pragma unroll
    for (int i = 0; i < 4; ++i)
#pragma unroll
        for (int j = 0; j < 4; ++j) acc[i][j] = (f32x4){0.f, 0.f, 0.f, 0.f};

    const short* Ag = hact + ((size_t)head * B_ + (size_t)mt * 128) * H_;
    const short* Bg = w2t  + ((size_t)head * D_ + (size_t)nt * 128) * H_;

    stage64<512>(Ag, 0, sm, t);
    stage64<512>(Bg, 0, sm + 16384, t);
    __syncthreads();

#pragma unroll
    for (int kt = 0; kt < 8; ++kt) {
        short* Asl = sm + (kt & 1) * 8192;
        short* Bsl = sm + 16384 + (kt & 1) * 8192;
        if (kt < 7) {   // prefetch next tile into other slot BEFORE compute
            stage64<512>(Ag, (kt + 1) * 64, sm + ((kt + 1) & 1) * 8192, t);
            stage64<512>(Bg, (kt + 1) * 64, sm + 16384 + ((kt + 1) & 1) * 8192, t);
        }
#pragma unroll
        for (int kh = 0; kh < 2; ++kh) {
            int g = kh * 4 + kq;
            bf16x8 aF[4], bF[4];
#pragma unroll
            for (int j = 0; j < 4; ++j)
                bF[j] = rdg<8>(Bsl, rowB0 + j * 16 + l16, g);
#pragma unroll
            for (int i = 0; i < 4; ++i)
                aF[i] = rdg<8>(Asl, rowA0 + i * 16 + l16, g);
#pragma unroll
            for (int i = 0; i < 4; ++i)
#pragma unroll
                for (int j = 0; j < 4; ++j)
                    acc[i][j] = mfma(aF[i], bF[j], acc[i][j]);
        }
        __syncthreads();   // drains prefetch loads + protects WAR
    }

#pragma unroll
    for (int mf = 0; mf < 4; ++mf) {
        int m = mt * 128 + wm * 64 + mf * 16 + kq * 4;
#pragma unroll
        for (int nf = 0; nf < 4; ++nf) {
            int d = nt * 128 + wn * 64 + nf * 16 + l16;
#pragma unroll
            for (int r = 0; r < 4; ++r) {
                float v = acc[mf][nf][r]
                        + bf2f(pb[((size_t)head * B_ + m + r) * D_ + d]);
                out[(size_t)(m + r) * (N_ * D_) + head * D_ + d] = v;
            }
        }
    }
}

// ---------------------------------------------------------------------------
extern "C" void kernel_launch(void* const* d_in, const int* in_sizes, int n_in,
                              void* d_out, int out_size, void* d_ws, size_t ws_size,
                              hipStream_t stream) {
    const float* x   = (const float*)d_in[0];
    const float* n1w = (const float*)d_in[1];
    const float* n2w = (const float*)d_in[2];
    const float* w1  = (const float*)d_in[3];
    const float* w3  = (const float*)d_in[4];
    const float* w2  = (const float*)d_in[5];
    float* out = (float*)d_out;

    char* ws = (char*)d_ws;
    // ws layout (total ~268 MiB):
    short* wgu  = (short*)(ws);                       //  8 MiB (interleaved G/U)
    short* w2t  = (short*)(ws + (8ull   << 20));      //  4 MiB
    short* pn   = (short*)(ws + (12ull  << 20));      // 64 MiB (bf16, head-major)
    short* pb   = (short*)(ws + (76ull  << 20));      // 64 MiB (bf16, head-major)
    short* hact = (short*)(ws + (140ull << 20));      // 128 MiB (bf16, head-major)

    (void)hipFuncSetAttribute((const void*)k_gu,
                              hipFuncAttributeMaxDynamicSharedMemorySize, 81920);
    (void)hipFuncSetAttribute((const void*)k_dn,
                              hipFuncAttributeMaxDynamicSharedMemorySize, 65536);

    k_prep<<<(N_ * D_ * H_) / 256, 256, 0, stream>>>(w1, w3, w2, wgu, w2t);
    k_mix<<<B_, 256, 0, stream>>>(x, n1w, n2w,
                                  (unsigned int*)pb, (unsigned int*)pn);
    k_gu<<<N_ * (B_ / 128), 256, 81920, stream>>>(pn, wgu, hact);
    k_dn<<<N_ * (B_ / 128) * (D_ / 128), 256, 65536, stream>>>(hact, w2t, pb, out);
}

// Round 13
// 309.349 us; speedup vs baseline: 1.0293x; 1.0293x over previous
//
#include <hip/hip_runtime.h>
#include <hip/hip_bf16.h>

// Problem constants: x (B,N,D) fp32; per-head SwiGLU FFN H=512.
#define B_ 8192
#define N_ 16
#define D_ 256
#define H_ 512

using bf16x8 = __attribute__((ext_vector_type(8))) short;
using f32x4  = __attribute__((ext_vector_type(4))) float;

__device__ __forceinline__ void gload_lds16(const void* g, void* l) {
    __builtin_amdgcn_global_load_lds(
        (const __attribute__((address_space(1))) void*)g,
        (__attribute__((address_space(3))) void*)l, 16, 0, 0);
}

__device__ __forceinline__ short f2bf(float f) {
    unsigned int u = __float_as_uint(f);
    u += 0x7fffu + ((u >> 16) & 1u);   // round-to-nearest-even
    return (short)(u >> 16);
}

__device__ __forceinline__ float bf2f(short s) {
    return __uint_as_float(((unsigned int)(unsigned short)s) << 16);
}

__device__ __forceinline__ unsigned int pack2(float lo, float hi) {
    return (unsigned int)(unsigned short)f2bf(lo)
         | ((unsigned int)(unsigned short)f2bf(hi) << 16);
}

__device__ __forceinline__ f32x4 mfma(bf16x8 a, bf16x8 b, f32x4 c) {
    return __builtin_amdgcn_mfma_f32_16x16x32_bf16(a, b, c, 0, 0, 0);
}

// Swizzled fragment read from a [256 rows][8 granule] LDS panel: global
// granule g of row r lives in slot (g^r)&7. 0-conflict geometry (R10/R11).
__device__ __forceinline__ bf16x8 rdp(const short* base, int row, int g) {
    int gp = (g ^ row) & 7;
    return *(const bf16x8*)&base[(row << 6) + (gp << 3)];
}

// Stage one 128-row half (half = 0/1) of a [256][64] K-panel, global stride S,
// k-offset k0. Linear LDS dest + inverse-XOR source. 512 threads, 2 gloads.
template<int S>
__device__ __forceinline__ void stage_half(const short* __restrict__ gsrc,
                                           int k0, short* panel, int half,
                                           int t) {
#pragma unroll
    for (int rnd = 0; rnd < 2; ++rnd) {
        int flat = half * 1024 + rnd * 512 + t;
        int row = flat >> 3, g = flat & 7;
        int sg = (g ^ row) & 7;
        gload_lds16(gsrc + (size_t)row * S + k0 + sg * 8, panel + flat * 8);
    }
}

// Compiler-fenced schedule primitives (R7 race fix: memory clobber + pinning).
#define WAIT_VM0   do { asm volatile("s_waitcnt vmcnt(0)" ::: "memory");   \
                        __builtin_amdgcn_sched_barrier(0); } while (0)
#define WAIT_LGKM0 do { asm volatile("s_waitcnt lgkmcnt(0)" ::: "memory"); \
                        __builtin_amdgcn_sched_barrier(0); } while (0)
#define BARRIER    do { __builtin_amdgcn_sched_barrier(0);                 \
                        asm volatile("s_barrier" ::: "memory");            \
                        __builtin_amdgcn_sched_barrier(0); } while (0)

// ---------------------------------------------------------------------------
// 8-phase-class GEMM core (m201-style, 4 phases per BK=64 K-tile):
// 256x256 tile, 8 waves (2M x 4N), per-wave 128x64, acc[8][4].
// Per phase: ds_read subtile | stage ONE half-tile of kt+1 (2 gloads) ->
// lgkmcnt(0) -> setprio(1) 16 MFMA setprio(0) -> s_barrier.
// vmcnt(0) ONLY at the K-tile boundary (loads had ~4 phases to land).
// LDS 128 KiB: A dbuf [0,64K) bytes, B dbuf [64K,128K).
// ---------------------------------------------------------------------------
template<int NT, int SA, int SB>
__device__ __forceinline__ void gemm8p(const short* __restrict__ Ag,
                                       const short* __restrict__ Bg,
                                       short* sm, f32x4 (&acc)[8][4],
                                       int t) {
    int lane = t & 63;
    int l16 = lane & 15, kq = lane >> 4;
    int w = t >> 6;
    int rowA0 = (w >> 2) * 128;    // wm in {0,1}
    int rowB0 = (w & 3) * 64;      // wn in {0..3}

    // prologue: stage tile 0 into buf 0, drain, rendezvous
    stage_half<SA>(Ag, 0, sm, 0, t);
    stage_half<SA>(Ag, 0, sm, 1, t);
    stage_half<SB>(Bg, 0, sm + 32768, 0, t);
    stage_half<SB>(Bg, 0, sm + 32768, 1, t);
    WAIT_VM0;
    BARRIER;

#pragma unroll 1
    for (int kt = 0; kt < NT; ++kt) {
        short* As  = sm + (kt & 1) * 16384;
        short* Bs  = sm + 32768 + (kt & 1) * 16384;
        short* Asn = sm + ((kt + 1) & 1) * 16384;
        short* Bsn = sm + 32768 + ((kt + 1) & 1) * 16384;
        const bool pf = (kt + 1) < NT;
        const int kn = (kt + 1) * 64;

        bf16x8 aF[4][2], bF[2][2];

#define PHASE(MH, NH, STAGE_STMT)                                          \
    do {                                                                   \
        if (NH == 0) {                                                     \
            _Pragma("unroll")                                              \
            for (int i = 0; i < 4; ++i)                                    \
                _Pragma("unroll")                                          \
                for (int kh = 0; kh < 2; ++kh)                             \
                    aF[i][kh] = rdp(As, rowA0 + (MH) * 64 + i * 16 + l16,  \
                                    kh * 4 + kq);                          \
        }                                                                  \
        _Pragma("unroll")                                                  \
        for (int j = 0; j < 2; ++j)                                        \
            _Pragma("unroll")                                              \
            for (int kh = 0; kh < 2; ++kh)                                 \
                bF[j][kh] = rdp(Bs, rowB0 + (NH) * 32 + j * 16 + l16,      \
                                kh * 4 + kq);                              \
        STAGE_STMT;                                                        \
        WAIT_LGKM0;                                                        \
        __builtin_amdgcn_s_setprio(1);                                     \
        _Pragma("unroll")                                                  \
        for (int i = 0; i < 4; ++i)                                        \
            _Pragma("unroll")                                              \
            for (int j = 0; j < 2; ++j)                                    \
                _Pragma("unroll")                                          \
                for (int kh = 0; kh < 2; ++kh)                             \
                    acc[(MH) * 4 + i][(NH) * 2 + j] =                      \
                        mfma(aF[i][kh], bF[j][kh],                         \
                             acc[(MH) * 4 + i][(NH) * 2 + j]);             \
        __builtin_amdgcn_s_setprio(0);                                     \
        BARRIER;                                                           \
    } while (0)

        PHASE(0, 0, if (pf) stage_half<SA>(Ag, kn, Asn, 0, t));
        PHASE(0, 1, if (pf) stage_half<SA>(Ag, kn, Asn, 1, t));
        PHASE(1, 0, if (pf) stage_half<SB>(Bg, kn, Bsn, 0, t));
        PHASE(1, 1, if (pf) stage_half<SB>(Bg, kn, Bsn, 1, t));
#undef PHASE

        // K-tile boundary: drain next tile's loads (issued over the 4 phases
        // above), then rendezvous so every wave sees the staged buffer.
        if (pf) {
            WAIT_VM0;
            BARRIER;
        }
    }
}

// ---------------------------------------------------------------------------
// k_prep: fp32 weights -> bf16.
//   wgu: [n][1024 rows][256] where row ri = (h>>4)*32 + which*16 + (h&15),
//        which 0=W1(gate), 1=W3(up)  -> G/U rows adjacent at 16-granularity.
//   w2t: [n][d][h]  (B^T of (H,D))
// ---------------------------------------------------------------------------
__global__ __launch_bounds__(256) void k_prep(const float* __restrict__ w1,
                                              const float* __restrict__ w3,
                                              const float* __restrict__ w2,
                                              short* __restrict__ wgu,
                                              short* __restrict__ w2t) {
    int o = blockIdx.x * 256 + threadIdx.x;      // 0 .. N*D*H-1 (2M)
    int n = o >> 17;                              // / (D*H = 131072)
    int r = o & 131071;
    int h = r >> 8, d = r & 255;
    size_t base = ((size_t)n * 1024 + (h >> 4) * 32 + (h & 15)) * 256 + d;
    wgu[base]            = f2bf(w1[(size_t)n * 131072 + (size_t)d * 512 + h]);
    wgu[base + 16 * 256] = f2bf(w3[(size_t)n * 131072 + (size_t)d * 512 + h]);
    int d2 = r >> 9, h2 = r & 511;                // [n][d][h] out layout
    w2t[o] = f2bf(w2[(size_t)n * 131072 + (size_t)h2 * 256 + d2]);
}

// ---------------------------------------------------------------------------
// k_mix: per-b block. rmsnorm1 -> head_mixing -> +x -> rmsnorm2.
// Wave-parallel float4 row sums + bank-staggered mix loop + packed bf16x2
// stores. Head-major outputs pb/pn [head][b][d].
// ---------------------------------------------------------------------------
__global__ __launch_bounds__(256) void k_mix(const float* __restrict__ x,
                                             const float* __restrict__ n1w,
                                             const float* __restrict__ n2w,
                                             unsigned int* __restrict__ pb_u,
                                             unsigned int* __restrict__ pn_u) {
    __shared__ __align__(16) float xs[N_ * D_];
    __shared__ __align__(16) float ps[N_ * D_];
    __shared__ float inv1[N_];
    __shared__ float inv2[N_];
    int b = blockIdx.x;
    int t = threadIdx.x;
    int w = t >> 6, lane = t & 63;

    const float4* xb4 = (const float4*)(x + (size_t)b * (N_ * D_));
    float4* xs4 = (float4*)xs;
    float4* ps4 = (float4*)ps;
#pragma unroll
    for (int i = 0; i < 4; ++i) xs4[t + i * 256] = xb4[t + i * 256];
    __syncthreads();

#pragma unroll
    for (int q = 0; q < 4; ++q) {
        int row = w * 4 + q;
        float4 v = xs4[row * 64 + lane];
        float s = v.x * v.x + v.y * v.y + v.z * v.z + v.w * v.w;
        s += __shfl_xor(s, 1);  s += __shfl_xor(s, 2);
        s += __shfl_xor(s, 4);  s += __shfl_xor(s, 8);
        s += __shfl_xor(s, 16); s += __shfl_xor(s, 32);
        if (lane == 0) inv1[row] = rsqrtf(s * (1.0f / 256.0f) + 1e-6f);
    }
    __syncthreads();

    {
        int n = t >> 4, j = t & 15;
        float i1 = inv1[n];
#pragma unroll 1
        for (int m = 0; m < 16; ++m) {
            int mm = (m + n) & 15;
            float v = xs[n * 256 + mm * 16 + j] * i1 * n1w[mm * 16 + j]
                    + xs[mm * 256 + t];
            ps[mm * 256 + t] = v;
        }
    }
    __syncthreads();

#pragma unroll
    for (int q = 0; q < 4; ++q) {
        int row = w * 4 + q;
        float4 v = ps4[row * 64 + lane];
        float s = v.x * v.x + v.y * v.y + v.z * v.z + v.w * v.w;
        s += __shfl_xor(s, 1);  s += __shfl_xor(s, 2);
        s += __shfl_xor(s, 4);  s += __shfl_xor(s, 8);
        s += __shfl_xor(s, 16); s += __shfl_xor(s, 32);
        if (lane == 0) inv2[row] = rsqrtf(s * (1.0f / 256.0f) + 1e-6f);
    }
    __syncthreads();

    int dh = t & 127, mh = t >> 7;
    float wA = n2w[2 * dh], wB = n2w[2 * dh + 1];
#pragma unroll
    for (int i = 0; i < 8; ++i) {
        int m = mh * 8 + i;
        float2 f = *(const float2*)&ps[m * 256 + 2 * dh];
        float iv = inv2[m];
        size_t off = ((size_t)m * B_ + b) * (D_ / 2) + dh;
        pb_u[off] = pack2(f.x, f.y);
        pn_u[off] = pack2(f.x * iv * wA, f.y * iv * wB);
    }
}

// ---------------------------------------------------------------------------
// k_gu: [G|U] = Pn @ Wgu^T per head (M=8192/head, N=1024 interleaved, K=256),
// silu(G)*U epilogue -> hact [head][m][h] bf16. 256x256 tile, NT=4.
// ---------------------------------------------------------------------------
__global__ __launch_bounds__(512, 2) void k_gu(const short* __restrict__ pn,
                                               const short* __restrict__ wgu,
                                               short* __restrict__ hact) {
    extern __shared__ short sm[];

    // XCD-aware bijective swizzle: 2048 blocks, 256 per XCD chunk.
    int bid = blockIdx.x;
    int bx = (bid & 7) * 256 + (bid >> 3);
    int head = bx >> 7;
    int mt = (bx >> 2) & 31;
    int nt = bx & 3;

    int t = threadIdx.x;
    int lane = t & 63, w = t >> 6;
    int l16 = lane & 15, kq = lane >> 4;
    int wm = w >> 2, wn = w & 3;

    f32x4 acc[8][4];
#pragma unroll
    for (int i = 0; i < 8; ++i)
#pragma unroll
        for (int j = 0; j < 4; ++j) acc[i][j] = (f32x4){0.f, 0.f, 0.f, 0.f};

    const short* Ag = pn  + ((size_t)head * B_ + (size_t)mt * 256) * D_;
    const short* Bg = wgu + ((size_t)head * 1024 + (size_t)nt * 256) * D_;

    gemm8p<4, D_, D_>(Ag, Bg, sm, acc, t);

    // epilogue: nf pairs (0,1),(2,3) are (G,U) of the same 16 h's.
    size_t hb = (size_t)head * B_ * H_;
#pragma unroll
    for (int mf = 0; mf < 8; ++mf) {
        int m = mt * 256 + wm * 128 + mf * 16 + kq * 4;
#pragma unroll
        for (int p = 0; p < 2; ++p) {
            int h = (nt * 8 + wn * 2 + p) * 16 + l16;
#pragma unroll
            for (int r = 0; r < 4; ++r) {
                float g = acc[mf][2 * p][r];
                float u = acc[mf][2 * p + 1][r];
                float hv = g * (1.0f / (1.0f + __expf(-g))) * u;
                hact[hb + (size_t)(m + r) * H_ + h] = f2bf(hv);
            }
        }
    }
}

// ---------------------------------------------------------------------------
// k_dn: Q = Hact @ W2 per head (M=8192/head, N=256=D, K=512) + pb -> (B,N,D).
// 256x256 tile, NT=8.
// ---------------------------------------------------------------------------
__global__ __launch_bounds__(512, 2) void k_dn(const short* __restrict__ hact,
                                               const short* __restrict__ w2t,
                                               const short* __restrict__ pb,
                                               float* __restrict__ out) {
    extern __shared__ short sm[];

    // XCD-aware bijective swizzle: 512 blocks, 64 per XCD chunk.
    int bid = blockIdx.x;
    int bx = (bid & 7) * 64 + (bid >> 3);
    int head = bx >> 5;
    int mt = bx & 31;

    int t = threadIdx.x;
    int lane = t & 63, w = t >> 6;
    int l16 = lane & 15, kq = lane >> 4;
    int wm = w >> 2, wn = w & 3;

    f32x4 acc[8][4];
#pragma unroll
    for (int i = 0; i < 8; ++i)
#pragma unroll
        for (int j = 0; j < 4; ++j) acc[i][j] = (f32x4){0.f, 0.f, 0.f, 0.f};

    const short* Ag = hact + ((size_t)head * B_ + (size_t)mt * 256) * H_;
    const short* Bg = w2t  + (size_t)head * D_ * H_;

    gemm8p<8, H_, H_>(Ag, Bg, sm, acc, t);

#pragma unroll
    for (int mf = 0; mf < 8; ++mf) {
        int m = mt * 256 + wm * 128 + mf * 16 + kq * 4;
#pragma unroll
        for (int nf = 0; nf < 4; ++nf) {
            int d = wn * 64 + nf * 16 + l16;
#pragma unroll
            for (int r = 0; r < 4; ++r) {
                float v = acc[mf][nf][r]
                        + bf2f(pb[((size_t)head * B_ + m + r) * D_ + d]);
                out[(size_t)(m + r) * (N_ * D_) + head * D_ + d] = v;
            }
        }
    }
}

// ---------------------------------------------------------------------------
extern "C" void kernel_launch(void* const* d_in, const int* in_sizes, int n_in,
                              void* d_out, int out_size, void* d_ws, size_t ws_size,
                              hipStream_t stream) {
    const float* x   = (const float*)d_in[0];
    const float* n1w = (const float*)d_in[1];
    const float* n2w = (const float*)d_in[2];
    const float* w1  = (const float*)d_in[3];
    const float* w3  = (const float*)d_in[4];
    const float* w2  = (const float*)d_in[5];
    float* out = (float*)d_out;

    char* ws = (char*)d_ws;
    // ws layout (total ~268 MiB):
    short* wgu  = (short*)(ws);                       //  8 MiB (interleaved G/U)
    short* w2t  = (short*)(ws + (8ull   << 20));      //  4 MiB
    short* pn   = (short*)(ws + (12ull  << 20));      // 64 MiB (bf16, head-major)
    short* pb   = (short*)(ws + (76ull  << 20));      // 64 MiB (bf16, head-major)
    short* hact = (short*)(ws + (140ull << 20));      // 128 MiB (bf16, head-major)

    (void)hipFuncSetAttribute((const void*)k_gu,
                              hipFuncAttributeMaxDynamicSharedMemorySize, 131072);
    (void)hipFuncSetAttribute((const void*)k_dn,
                              hipFuncAttributeMaxDynamicSharedMemorySize, 131072);

    k_prep<<<(N_ * D_ * H_) / 256, 256, 0, stream>>>(w1, w3, w2, wgu, w2t);
    k_mix<<<B_, 256, 0, stream>>>(x, n1w, n2w,
                                  (unsigned int*)pb, (unsigned int*)pn);
    k_gu<<<N_ * (B_ / 256) * 4, 512, 131072, stream>>>(pn, wgu, hact);
    k_dn<<<N_ * (B_ / 256), 512, 131072, stream>>>(hact, w2t, pb, out);
}

// Round 14
// 297.541 us; speedup vs baseline: 1.0701x; 1.0397x over previous
//
#include <hip/hip_runtime.h>
#include <hip/hip_bf16.h>

// Problem constants: x (B,N,D) fp32; per-head SwiGLU FFN H=512.
#define B_ 8192
#define N_ 16
#define D_ 256
#define H_ 512

using bf16x8 = __attribute__((ext_vector_type(8))) short;
using f32x4  = __attribute__((ext_vector_type(4))) float;

__device__ __forceinline__ void gload_lds16(const void* g, void* l) {
    __builtin_amdgcn_global_load_lds(
        (const __attribute__((address_space(1))) void*)g,
        (__attribute__((address_space(3))) void*)l, 16, 0, 0);
}

__device__ __forceinline__ short f2bf(float f) {
    unsigned int u = __float_as_uint(f);
    u += 0x7fffu + ((u >> 16) & 1u);   // round-to-nearest-even
    return (short)(u >> 16);
}

__device__ __forceinline__ float bf2f(short s) {
    return __uint_as_float(((unsigned int)(unsigned short)s) << 16);
}

__device__ __forceinline__ unsigned int pack2(float lo, float hi) {
    return (unsigned int)(unsigned short)f2bf(lo)
         | ((unsigned int)(unsigned short)f2bf(hi) << 16);
}

__device__ __forceinline__ f32x4 mfma(bf16x8 a, bf16x8 b, f32x4 c) {
    return __builtin_amdgcn_mfma_f32_16x16x32_bf16(a, b, c, 0, 0, 0);
}

// Swizzled fragment read from a [256 rows][8 granule] LDS panel: global
// granule g of row r lives in slot (g^r)&7. 0-conflict geometry (R10/R11).
__device__ __forceinline__ bf16x8 rdp(const short* base, int row, int g) {
    int gp = (g ^ row) & 7;
    return *(const bf16x8*)&base[(row << 6) + (gp << 3)];
}

// Stage one 128-row half (half = 0/1) of a [256][64] K-panel, global stride S,
// k-offset k0. Linear LDS dest + inverse-XOR source. 512 threads, 2 gloads.
template<int S>
__device__ __forceinline__ void stage_half(const short* __restrict__ gsrc,
                                           int k0, short* panel, int half,
                                           int t) {
#pragma unroll
    for (int rnd = 0; rnd < 2; ++rnd) {
        int flat = half * 1024 + rnd * 512 + t;
        int row = flat >> 3, g = flat & 7;
        int sg = (g ^ row) & 7;
        gload_lds16(gsrc + (size_t)row * S + k0 + sg * 8, panel + flat * 8);
    }
}

// Fenced (correctness-bearing) primitives. NO sched_barrier pinning, NO
// manual lgkmcnt drains: ds_reads are plain loads so the compiler emits
// counted lgkmcnt itself (R13 post-mortem: manual drains = m141 regression).
#define WAIT_VM0 asm volatile("s_waitcnt vmcnt(0)" ::: "memory")
#define BARRIER  asm volatile("s_barrier" ::: "memory")

// ---------------------------------------------------------------------------
// 8-phase-class GEMM core, de-fenced (R14): 256x256 tile, BK=64, NT K-tiles,
// 8 waves (2M x 4N), per-wave 128x64, acc[8][4].
// Per phase: {ds_read subtile | stage ONE half-tile of kt+1 (2 gloads) ->
// setprio(1) 16 MFMA setprio(0) -> s_barrier}. vmcnt(0) ONLY at the K-tile
// boundary. Hazard protocol identical to R13 (passed): all reads of a slot
// complete before the boundary barrier that precedes its overwrite.
// LDS 128 KiB: A dbuf [0,64K) bytes, B dbuf [64K,128K).
// ---------------------------------------------------------------------------
template<int NT, int SA, int SB>
__device__ __forceinline__ void gemm8p(const short* __restrict__ Ag,
                                       const short* __restrict__ Bg,
                                       short* sm, f32x4 (&acc)[8][4],
                                       int t) {
    int lane = t & 63;
    int l16 = lane & 15, kq = lane >> 4;
    int w = t >> 6;
    int rowA0 = (w >> 2) * 128;    // wm in {0,1}
    int rowB0 = (w & 3) * 64;      // wn in {0..3}

    // prologue: stage tile 0 into buf 0, drain, rendezvous
    stage_half<SA>(Ag, 0, sm, 0, t);
    stage_half<SA>(Ag, 0, sm, 1, t);
    stage_half<SB>(Bg, 0, sm + 32768, 0, t);
    stage_half<SB>(Bg, 0, sm + 32768, 1, t);
    WAIT_VM0;
    BARRIER;

#pragma unroll
    for (int kt = 0; kt < NT; ++kt) {
        short* As  = sm + (kt & 1) * 16384;
        short* Bs  = sm + 32768 + (kt & 1) * 16384;
        short* Asn = sm + ((kt + 1) & 1) * 16384;
        short* Bsn = sm + 32768 + ((kt + 1) & 1) * 16384;
        const bool pf = (kt + 1) < NT;
        const int kn = (kt + 1) * 64;

        bf16x8 aF[4][2], bF[2][2];

#define PHASE(MH, NH, STAGE_STMT)                                          \
    do {                                                                   \
        if ((NH) == 0) {                                                   \
            _Pragma("unroll")                                              \
            for (int i = 0; i < 4; ++i)                                    \
                _Pragma("unroll")                                          \
                for (int kh = 0; kh < 2; ++kh)                             \
                    aF[i][kh] = rdp(As, rowA0 + (MH) * 64 + i * 16 + l16,  \
                                    kh * 4 + kq);                          \
        }                                                                  \
        _Pragma("unroll")                                                  \
        for (int j = 0; j < 2; ++j)                                        \
            _Pragma("unroll")                                              \
            for (int kh = 0; kh < 2; ++kh)                                 \
                bF[j][kh] = rdp(Bs, rowB0 + (NH) * 32 + j * 16 + l16,      \
                                kh * 4 + kq);                              \
        STAGE_STMT;                                                        \
        __builtin_amdgcn_s_setprio(1);                                     \
        _Pragma("unroll")                                                  \
        for (int i = 0; i < 4; ++i)                                        \
            _Pragma("unroll")                                              \
            for (int j = 0; j < 2; ++j)                                    \
                _Pragma("unroll")                                          \
                for (int kh = 0; kh < 2; ++kh)                             \
                    acc[(MH) * 4 + i][(NH) * 2 + j] =                      \
                        mfma(aF[i][kh], bF[j][kh],                         \
                             acc[(MH) * 4 + i][(NH) * 2 + j]);             \
        __builtin_amdgcn_s_setprio(0);                                     \
        BARRIER;                                                           \
    } while (0)

        PHASE(0, 0, if (pf) stage_half<SA>(Ag, kn, Asn, 0, t));
        PHASE(0, 1, if (pf) stage_half<SA>(Ag, kn, Asn, 1, t));
        PHASE(1, 0, if (pf) stage_half<SB>(Bg, kn, Bsn, 0, t));
        PHASE(1, 1, if (pf) stage_half<SB>(Bg, kn, Bsn, 1, t));
#undef PHASE

        // K-tile boundary: drain next tile's loads (issued across the 4
        // phases above), rendezvous so every wave sees the staged buffer.
        if (pf) {
            WAIT_VM0;
            BARRIER;
        }
    }
}

// ---------------------------------------------------------------------------
// k_prep: fp32 weights -> bf16.
//   wgu: [n][1024 rows][256] where row ri = (h>>4)*32 + which*16 + (h&15),
//        which 0=W1(gate), 1=W3(up)  -> G/U rows adjacent at 16-granularity.
//   w2t: [n][d][h]  (B^T of (H,D))
// ---------------------------------------------------------------------------
__global__ __launch_bounds__(256) void k_prep(const float* __restrict__ w1,
                                              const float* __restrict__ w3,
                                              const float* __restrict__ w2,
                                              short* __restrict__ wgu,
                                              short* __restrict__ w2t) {
    int o = blockIdx.x * 256 + threadIdx.x;      // 0 .. N*D*H-1 (2M)
    int n = o >> 17;                              // / (D*H = 131072)
    int r = o & 131071;
    int h = r >> 8, d = r & 255;
    size_t base = ((size_t)n * 1024 + (h >> 4) * 32 + (h & 15)) * 256 + d;
    wgu[base]            = f2bf(w1[(size_t)n * 131072 + (size_t)d * 512 + h]);
    wgu[base + 16 * 256] = f2bf(w3[(size_t)n * 131072 + (size_t)d * 512 + h]);
    int d2 = r >> 9, h2 = r & 511;                // [n][d][h] out layout
    w2t[o] = f2bf(w2[(size_t)n * 131072 + (size_t)h2 * 256 + d2]);
}

// ---------------------------------------------------------------------------
// k_mix: per-b block. rmsnorm1 -> head_mixing -> +x -> rmsnorm2.
// Wave-parallel float4 row sums + bank-staggered mix loop + packed bf16x2
// stores. Head-major outputs pb/pn [head][b][d].
// ---------------------------------------------------------------------------
__global__ __launch_bounds__(256) void k_mix(const float* __restrict__ x,
                                             const float* __restrict__ n1w,
                                             const float* __restrict__ n2w,
                                             unsigned int* __restrict__ pb_u,
                                             unsigned int* __restrict__ pn_u) {
    __shared__ __align__(16) float xs[N_ * D_];
    __shared__ __align__(16) float ps[N_ * D_];
    __shared__ float inv1[N_];
    __shared__ float inv2[N_];
    int b = blockIdx.x;
    int t = threadIdx.x;
    int w = t >> 6, lane = t & 63;

    const float4* xb4 = (const float4*)(x + (size_t)b * (N_ * D_));
    float4* xs4 = (float4*)xs;
    float4* ps4 = (float4*)ps;
#pragma unroll
    for (int i = 0; i < 4; ++i) xs4[t + i * 256] = xb4[t + i * 256];
    __syncthreads();

#pragma unroll
    for (int q = 0; q < 4; ++q) {
        int row = w * 4 + q;
        float4 v = xs4[row * 64 + lane];
        float s = v.x * v.x + v.y * v.y + v.z * v.z + v.w * v.w;
        s += __shfl_xor(s, 1);  s += __shfl_xor(s, 2);
        s += __shfl_xor(s, 4);  s += __shfl_xor(s, 8);
        s += __shfl_xor(s, 16); s += __shfl_xor(s, 32);
        if (lane == 0) inv1[row] = rsqrtf(s * (1.0f / 256.0f) + 1e-6f);
    }
    __syncthreads();

    {
        int n = t >> 4, j = t & 15;
        float i1 = inv1[n];
#pragma unroll 1
        for (int m = 0; m < 16; ++m) {
            int mm = (m + n) & 15;
            float v = xs[n * 256 + mm * 16 + j] * i1 * n1w[mm * 16 + j]
                    + xs[mm * 256 + t];
            ps[mm * 256 + t] = v;
        }
    }
    __syncthreads();

#pragma unroll
    for (int q = 0; q < 4; ++q) {
        int row = w * 4 + q;
        float4 v = ps4[row * 64 + lane];
        float s = v.x * v.x + v.y * v.y + v.z * v.z + v.w * v.w;
        s += __shfl_xor(s, 1);  s += __shfl_xor(s, 2);
        s += __shfl_xor(s, 4);  s += __shfl_xor(s, 8);
        s += __shfl_xor(s, 16); s += __shfl_xor(s, 32);
        if (lane == 0) inv2[row] = rsqrtf(s * (1.0f / 256.0f) + 1e-6f);
    }
    __syncthreads();

    int dh = t & 127, mh = t >> 7;
    float wA = n2w[2 * dh], wB = n2w[2 * dh + 1];
#pragma unroll
    for (int i = 0; i < 8; ++i) {
        int m = mh * 8 + i;
        float2 f = *(const float2*)&ps[m * 256 + 2 * dh];
        float iv = inv2[m];
        size_t off = ((size_t)m * B_ + b) * (D_ / 2) + dh;
        pb_u[off] = pack2(f.x, f.y);
        pn_u[off] = pack2(f.x * iv * wA, f.y * iv * wB);
    }
}

// ---------------------------------------------------------------------------
// k_gu: [G|U] = Pn @ Wgu^T per head (M=8192/head, N=1024 interleaved, K=256),
// silu(G)*U epilogue -> hact [head][m][h] bf16. 256x256 tile, NT=4.
// ---------------------------------------------------------------------------
__global__ __launch_bounds__(512, 2) void k_gu(const short* __restrict__ pn,
                                               const short* __restrict__ wgu,
                                               short* __restrict__ hact) {
    extern __shared__ short sm[];

    // XCD-aware bijective swizzle: 2048 blocks, 256 per XCD chunk.
    int bid = blockIdx.x;
    int bx = (bid & 7) * 256 + (bid >> 3);
    int head = bx >> 7;
    int mt = (bx >> 2) & 31;
    int nt = bx & 3;

    int t = threadIdx.x;
    int lane = t & 63, w = t >> 6;
    int l16 = lane & 15, kq = lane >> 4;
    int wm = w >> 2, wn = w & 3;

    f32x4 acc[8][4];
#pragma unroll
    for (int i = 0; i < 8; ++i)
#pragma unroll
        for (int j = 0; j < 4; ++j) acc[i][j] = (f32x4){0.f, 0.f, 0.f, 0.f};

    const short* Ag = pn  + ((size_t)head * B_ + (size_t)mt * 256) * D_;
    const short* Bg = wgu + ((size_t)head * 1024 + (size_t)nt * 256) * D_;

    gemm8p<4, D_, D_>(Ag, Bg, sm, acc, t);

    // epilogue: nf pairs (0,1),(2,3) are (G,U) of the same 16 h's.
    size_t hb = (size_t)head * B_ * H_;
#pragma unroll
    for (int mf = 0; mf < 8; ++mf) {
        int m = mt * 256 + wm * 128 + mf * 16 + kq * 4;
#pragma unroll
        for (int p = 0; p < 2; ++p) {
            int h = (nt * 8 + wn * 2 + p) * 16 + l16;
#pragma unroll
            for (int r = 0; r < 4; ++r) {
                float g = acc[mf][2 * p][r];
                float u = acc[mf][2 * p + 1][r];
                float hv = g * (1.0f / (1.0f + __expf(-g))) * u;
                hact[hb + (size_t)(m + r) * H_ + h] = f2bf(hv);
            }
        }
    }
}

// ---------------------------------------------------------------------------
// k_dn: Q = Hact @ W2 per head (M=8192/head, N=256=D, K=512) + pb -> (B,N,D).
// 256x256 tile, NT=8.
// ---------------------------------------------------------------------------
__global__ __launch_bounds__(512, 2) void k_dn(const short* __restrict__ hact,
                                               const short* __restrict__ w2t,
                                               const short* __restrict__ pb,
                                               float* __restrict__ out) {
    extern __shared__ short sm[];

    // XCD-aware bijective swizzle: 512 blocks, 64 per XCD chunk.
    int bid = blockIdx.x;
    int bx = (bid & 7) * 64 + (bid >> 3);
    int head = bx >> 5;
    int mt = bx & 31;

    int t = threadIdx.x;
    int lane = t & 63, w = t >> 6;
    int l16 = lane & 15, kq = lane >> 4;
    int wm = w >> 2, wn = w & 3;

    f32x4 acc[8][4];
#pragma unroll
    for (int i = 0; i < 8; ++i)
#pragma unroll
        for (int j = 0; j < 4; ++j) acc[i][j] = (f32x4){0.f, 0.f, 0.f, 0.f};

    const short* Ag = hact + ((size_t)head * B_ + (size_t)mt * 256) * H_;
    const short* Bg = w2t  + (size_t)head * D_ * H_;

    gemm8p<8, H_, H_>(Ag, Bg, sm, acc, t);

#pragma unroll
    for (int mf = 0; mf < 8; ++mf) {
        int m = mt * 256 + wm * 128 + mf * 16 + kq * 4;
#pragma unroll
        for (int nf = 0; nf < 4; ++nf) {
            int d = wn * 64 + nf * 16 + l16;
#pragma unroll
            for (int r = 0; r < 4; ++r) {
                float v = acc[mf][nf][r]
                        + bf2f(pb[((size_t)head * B_ + m + r) * D_ + d]);
                out[(size_t)(m + r) * (N_ * D_) + head * D_ + d] = v;
            }
        }
    }
}

// ---------------------------------------------------------------------------
extern "C" void kernel_launch(void* const* d_in, const int* in_sizes, int n_in,
                              void* d_out, int out_size, void* d_ws, size_t ws_size,
                              hipStream_t stream) {
    const float* x   = (const float*)d_in[0];
    const float* n1w = (const float*)d_in[1];
    const float* n2w = (const float*)d_in[2];
    const float* w1  = (const float*)d_in[3];
    const float* w3  = (const float*)d_in[4];
    const float* w2  = (const float*)d_in[5];
    float* out = (float*)d_out;

    char* ws = (char*)d_ws;
    // ws layout (total ~268 MiB):
    short* wgu  = (short*)(ws);                       //  8 MiB (interleaved G/U)
    short* w2t  = (short*)(ws + (8ull   << 20));      //  4 MiB
    short* pn   = (short*)(ws + (12ull  << 20));      // 64 MiB (bf16, head-major)
    short* pb   = (short*)(ws + (76ull  << 20));      // 64 MiB (bf16, head-major)
    short* hact = (short*)(ws + (140ull << 20));      // 128 MiB (bf16, head-major)

    (void)hipFuncSetAttribute((const void*)k_gu,
                              hipFuncAttributeMaxDynamicSharedMemorySize, 131072);
    (void)hipFuncSetAttribute((const void*)k_dn,
                              hipFuncAttributeMaxDynamicSharedMemorySize, 131072);

    k_prep<<<(N_ * D_ * H_) / 256, 256, 0, stream>>>(w1, w3, w2, wgu, w2t);
    k_mix<<<B_, 256, 0, stream>>>(x, n1w, n2w,
                                  (unsigned int*)pb, (unsigned int*)pn);
    k_gu<<<N_ * (B_ / 256) * 4, 512, 131072, stream>>>(pn, wgu, hact);
    k_dn<<<N_ * (B_ / 256), 512, 131072, stream>>>(hact, w2t, pb, out);
}